// Round 8
// baseline (171.183 us; speedup 1.0000x reference)
//
#include <hip/hip_runtime.h>

// YOLO-style loss: y_pred (1024,28,28,30) f32, y_true (1024,28,28,5) f32 -> scalar f32.
// ~113 MB read; L3 absorbs ~half -> BW floor ~10-15us; harness fixed overhead
// (385MB 0xAA ws-fill ~57us + 226MB input restore ~35us) ~= 92-110us of dur_us.
// R1 55us strided (VMEM-line-bound). R2 65us atomics (VALUBusy 11%, occ 29% -> stall-bound).
// R3 45us. R4 40us global_load_lds. R5 38us barrier-free. R6 pipelined: NEUTRAL.
// R7 cycle-diet: NEUTRAL. Three structural rewrites invariant at ~39us while all
// throughput models say <=20us -> kernel-internal code is not the limiter.
// R8: test the last controllable hypothesis = per-dispatch overhead. ONE dispatch:
// 512 persistent blocks, grid-stride over 12544 wave-tiles (R7 body), block partials
// in d_ws, last-block reduction. Last-block detection exploits the documented 0xAA
// re-poison: counter starts at 0xAAAAAAAA each call; block seeing old==0xAAAAAAAA+511
// is last. Loud failure mode (no d_out write) if poison assumption breaks.

#define S_GRID 28
#define N_CELLS (1024 * S_GRID * S_GRID)     // 802816
#define CPW 64                               // cells per tile (= lanes)
#define NT (N_CELLS / CPW)                   // 12544 tiles
#define WPB 4
#define BLOCK (WPB * 64)                     // 256
#define GRID_B 512                           // persistent blocks
#define TOTW (GRID_B * WPB)                  // 2048 waves -> 6.125 tiles/wave
#define POISON_LAST (0xAAAAAAAAu + (unsigned)(GRID_B - 1))

__device__ __forceinline__ float iou_calc(float bx, float by, float bw, float bh,
                                          float tx, float ty, float tw, float th,
                                          float gi, float gj) {
    float acx = (gj + bx) * 8.0f;
    float acy = (gi + by) * 8.0f;
    float aw  = bw * 224.0f;
    float ah  = bh * 224.0f;
    float ax1 = acx - aw * 0.5f, ax2 = acx + aw * 0.5f;
    float ay1 = acy - ah * 0.5f, ay2 = acy + ah * 0.5f;
    float bcx = (gj + tx) * 8.0f;
    float bcy = (gi + ty) * 8.0f;
    float btw = tw * 224.0f;
    float bth = th * 224.0f;
    float bx1 = bcx - btw * 0.5f, bx2 = bcx + btw * 0.5f;
    float by1 = bcy - bth * 0.5f, by2 = bcy + bth * 0.5f;

    float iw = fmaxf(fminf(ax2, bx2) - fmaxf(ax1, bx1), 0.0f);
    float ih = fmaxf(fminf(ay2, by2) - fmaxf(ay1, by1), 0.0f);
    float inter = iw * ih;
    float area_a = fmaxf(ax2 - ax1, 0.0f) * fmaxf(ay2 - ay1, 0.0f);
    float area_b = fmaxf(bx2 - bx1, 0.0f) * fmaxf(by2 - by1, 0.0f);
    return inter / (area_a + area_b - inter + 1e-12f);
}

__global__ __launch_bounds__(BLOCK) void yolo_loss_kernel(const float2* __restrict__ yp2,
                                                          const float2* __restrict__ yt2,
                                                          float* __restrict__ partials,
                                                          unsigned int* __restrict__ counter,
                                                          float* __restrict__ out) {
    __shared__ float sp[WPB][CPW * 30];      // 7680 B / wave, raw layout
    __shared__ float st[WPB][CPW * 5];       // 1280 B / wave, raw layout
    __shared__ float wsum[WPB];
    __shared__ unsigned int is_last;

    int tid  = threadIdx.x;
    int lane = tid & 63;
    int wave = tid >> 6;
    int gwid = blockIdx.x * WPB + wave;      // 0..2047

    float2* spw = (float2*)sp[wave];
    float2* stw = (float2*)st[wave];

    float acc = 0.0f;

    for (int t = gwid; t < NT; t += TOTW) {
        // ---- coalesced loads: 960 float2 pred, 160 float2 true per tile ----
        const float2* pb = yp2 + (size_t)t * 960;
        float2 v[15];
#pragma unroll
        for (int k = 0; k < 15; ++k) v[k] = pb[k * 64 + lane];

        const float2* tb = yt2 + (size_t)t * 160;
        float2 u0 = tb[lane];
        float2 u1 = tb[64 + lane];
        float2 u2 = (lane < 32) ? tb[128 + lane] : make_float2(0.0f, 0.0f);

        // ---- wave-private LDS staging, raw layout (conflict-free writes) ----
#pragma unroll
        for (int k = 0; k < 15; ++k) spw[k * 64 + lane] = v[k];
        stw[lane] = u0;
        stw[64 + lane] = u1;
        if (lane < 32) stw[128 + lane] = u2;
        // same-wave DS ordering: compiler lgkmcnt waits; no barrier.

        // ---- read own cell ----
        float pr[30];
        const float2* pc = (const float2*)(sp[wave] + lane * 30);
#pragma unroll
        for (int k = 0; k < 15; ++k) {
            float2 w = pc[k];
            pr[2 * k] = w.x;
            pr[2 * k + 1] = w.y;
        }
        const float* tcell = st[wave] + lane * 5;
        float tc = tcell[0], tx = tcell[1], ty = tcell[2], tw = tcell[3], th = tcell[4];

        // ---- per-cell loss ----
        int cell = t * CPW + lane;
        int ij = cell % (S_GRID * S_GRID);
        float gi = (float)(ij / S_GRID);
        float gj = (float)(ij % S_GRID);

        float iou0 = iou_calc(pr[0], pr[1], pr[2], pr[3], tx, ty, tw, th, gi, gj);
        float iou1 = iou_calc(pr[5], pr[6], pr[7], pr[8], tx, ty, tw, th, gi, gj);
        bool choose1 = !(iou0 > iou1);

        float conf_pred = choose1 ? pr[9] : pr[4];
        float conf_true = choose1 ? iou1 : iou0;
        float xp = choose1 ? pr[5] : pr[0];
        float yp = choose1 ? pr[6] : pr[1];

        float dcf = conf_pred - conf_true;
        float d0 = xp - tx, d1 = yp - ty;

        // class loss: sumsq - 2*p[cls] + 1 (one dynamic LDS read)
        float sumsq = 0.0f;
#pragma unroll
        for (int k = 10; k < 30; ++k) sumsq = fmaf(pr[k], pr[k], sumsq);
        int cls = (int)tc - 1;
        int cidx = cls < 0 ? 0 : cls;
        float pcls = sp[wave][lane * 30 + 10 + cidx];
        float lcls = (cls >= 0) ? (sumsq - 2.0f * pcls + 1.0f) : sumsq;

        float obj_loss   = dcf * dcf + 5.0f * (d0 * d0 + d1 * d1) + lcls;
        float noobj_loss = 0.5f * (pr[4] * pr[4] + pr[9] * pr[9]);
        acc += (tc != 0.0f) ? obj_loss : noobj_loss;
    }

    // ---- block reduction ----
#pragma unroll
    for (int off = 32; off > 0; off >>= 1) {
        acc += __shfl_down(acc, off, 64);
    }
    if (lane == 0) wsum[wave] = acc;
    __syncthreads();

    // ---- publish partial + last-block detection via poisoned counter ----
    if (tid == 0) {
        partials[blockIdx.x] = wsum[0] + wsum[1] + wsum[2] + wsum[3];
        __threadfence();                                   // release partial
        unsigned int old = atomicAdd(counter, 1u);         // device-scope
        is_last = (old == POISON_LAST) ? 1u : 0u;
    }
    __syncthreads();

    if (is_last) {
        __threadfence();                                   // acquire all partials
        float s = partials[tid] + partials[tid + 256];     // 512 partials, 2/thread
#pragma unroll
        for (int off = 32; off > 0; off >>= 1) {
            s += __shfl_down(s, off, 64);
        }
        if (lane == 0) wsum[wave] = s;
        __syncthreads();
        if (tid == 0) {
            out[0] = (wsum[0] + wsum[1] + wsum[2] + wsum[3]) * (1.0f / 1024.0f);
        }
    }
}

extern "C" void kernel_launch(void* const* d_in, const int* in_sizes, int n_in,
                              void* d_out, int out_size, void* d_ws, size_t ws_size,
                              hipStream_t stream) {
    const float2* y_pred = (const float2*)d_in[0];
    const float2* y_true = (const float2*)d_in[1];
    float* out = (float*)d_out;
    float* partials = (float*)d_ws;                                   // 512 floats
    unsigned int* counter = (unsigned int*)((char*)d_ws + 65536);     // own cache line region

    yolo_loss_kernel<<<GRID_B, BLOCK, 0, stream>>>(y_pred, y_true, partials, counter, out);
}

// Round 10
// 152.735 us; speedup vs baseline: 1.1208x; 1.1208x over previous
//
#include <hip/hip_runtime.h>

// YOLO-style loss: y_pred (1024,28,28,30) f32, y_true (1024,28,28,5) f32 -> scalar f32.
// ~113 MB read; harness fixed overhead ~106-110us of dur_us.
// R8 direct measurement: VALUBusy 4.8% (=3.2us busy), occ 17.9%, HBM 10.6% -> the
// kernel is ~95% stalled = latency-bound. Scaling evidence: 8 waves/CU -> 65us,
// 16 waves/CU -> ~38us: time ~ 1/waves. R6/R7 (per-wave restructures) neutral.
// R9/R10: double resident waves. LDS/wave 8.96KB -> 3.84KB via 32-cells-per-wave
// lane-pair split (even lane: ch0-14 + cell math; odd lane: ch15-29 squares,
// merged by one shfl). 15.4KB/block -> 8 blocks/CU = 32 waves/CU.
// __launch_bounds__(256,8) caps VGPR at 64 (8 waves/SIMD). No barriers.
// R10 fixes R9's param-shadowing compile error; p[10+cls] now read from LDS.

#define S_GRID 28
#define N_CELLS (1024 * S_GRID * S_GRID)     // 802816
#define CPT 32                               // cells per tile (= per wave)
#define NT2 (N_CELLS / CPT)                  // 25088 tiles
#define WPB 4
#define BLOCK (WPB * 64)                     // 256
#define NBLOCKS (NT2 / WPB)                  // 6272

__device__ __forceinline__ float iou_calc(float bx, float by, float bw, float bh,
                                          float tx, float ty, float tw, float th,
                                          float gi, float gj) {
    float acx = (gj + bx) * 8.0f;
    float acy = (gi + by) * 8.0f;
    float aw  = bw * 224.0f;
    float ah  = bh * 224.0f;
    float ax1 = acx - aw * 0.5f, ax2 = acx + aw * 0.5f;
    float ay1 = acy - ah * 0.5f, ay2 = acy + ah * 0.5f;
    float bcx = (gj + tx) * 8.0f;
    float bcy = (gi + ty) * 8.0f;
    float btw = tw * 224.0f;
    float bth = th * 224.0f;
    float bx1 = bcx - btw * 0.5f, bx2 = bcx + btw * 0.5f;
    float by1 = bcy - bth * 0.5f, by2 = bcy + bth * 0.5f;

    float iw = fmaxf(fminf(ax2, bx2) - fmaxf(ax1, bx1), 0.0f);
    float ih = fmaxf(fminf(ay2, by2) - fmaxf(ay1, by1), 0.0f);
    float inter = iw * ih;
    float area_a = fmaxf(ax2 - ax1, 0.0f) * fmaxf(ay2 - ay1, 0.0f);
    float area_b = fmaxf(bx2 - bx1, 0.0f) * fmaxf(by2 - by1, 0.0f);
    return inter / (area_a + area_b - inter + 1e-12f);
}

__global__ __launch_bounds__(BLOCK, 8) void yolo_loss_kernel(const float2* __restrict__ yp2,
                                                             const float* __restrict__ yt,
                                                             float* __restrict__ partials) {
    // per-wave slab: 32 cells x 30 floats = 3840 B; 15360 B/block -> 8 blocks/CU
    __shared__ float sp[WPB][CPT * 30];

    int tid   = threadIdx.x;
    int lane  = tid & 63;
    int wave  = tid >> 6;
    int tile  = blockIdx.x * WPB + wave;     // 0..25087
    int qcell = lane >> 1;                   // local cell 0..31
    int half  = lane & 1;                    // 0: ch0-14 owner, 1: ch15-29
    int cell  = tile * CPT + qcell;

    // ---- stage tile: 480 float2, coalesced (512B/instr, 8 lines) ----
    const float2* pb = yp2 + (size_t)tile * (CPT * 30 / 2);   // 480 f2
    float2* spw = (float2*)sp[wave];
#pragma unroll
    for (int k = 0; k < 8; ++k) {
        int idx = k * 64 + lane;
        if (idx < 480) spw[idx] = pb[idx];
    }
    // same-wave DS ordering; no barrier needed.

    // ---- each lane reads its 15 channels: base_f .. base_f+14 ----
    int base_f = qcell * 30 + half * 15;
    const float*  spf  = sp[wave];
    const float2* spf2 = (const float2*)sp[wave];
    int f2s = (base_f + 1) >> 1;             // works for both parities
    float s[15];
    {
        float2 r[7];
#pragma unroll
        for (int j = 0; j < 7; ++j) r[j] = spf2[f2s + j];
        float rs = spf[half ? base_f : base_f + 14];
        if (half == 0) {
            // even: ch0..13 from r, ch14 = rs
#pragma unroll
            for (int j = 0; j < 7; ++j) { s[2 * j] = r[j].x; s[2 * j + 1] = r[j].y; }
            s[14] = rs;
        } else {
            // odd: ch15 = rs, ch16..29 from r
            s[0] = rs;
#pragma unroll
            for (int j = 0; j < 7; ++j) { s[1 + 2 * j] = r[j].x; s[2 + 2 * j] = r[j].y; }
        }
    }

    // ---- class square partial: even lanes ch10-14 (s[10..14]), odd all 15 ----
    float csum = 0.0f;
#pragma unroll
    for (int j = 0; j < 15; ++j) {
        bool inc = (half != 0) || (j >= 10);
        float q = inc ? s[j] : 0.0f;
        csum = fmaf(q, q, csum);
    }
    float csum_tot = csum + __shfl_down(csum, 1, 64);   // even lane: full 20-ch sumsq

    // ---- per-cell finalization on even lanes only ----
    float val = 0.0f;
    if (half == 0) {
        const float* t = yt + (size_t)cell * 5;          // 32 lanes, 10-line span
        float tc = t[0], tx = t[1], ty = t[2], tw = t[3], th = t[4];

        int ij = cell % (S_GRID * S_GRID);
        float gi = (float)(ij / S_GRID);
        float gj = (float)(ij % S_GRID);

        float iou0 = iou_calc(s[0], s[1], s[2], s[3], tx, ty, tw, th, gi, gj);
        float iou1 = iou_calc(s[5], s[6], s[7], s[8], tx, ty, tw, th, gi, gj);
        bool choose1 = !(iou0 > iou1);

        float conf_pred = choose1 ? s[9] : s[4];
        float conf_true = choose1 ? iou1 : iou0;
        float xpred = choose1 ? s[5] : s[0];
        float ypred = choose1 ? s[6] : s[1];

        float dcf = conf_pred - conf_true;
        float d0 = xpred - tx, d1 = ypred - ty;

        int cls = (int)tc - 1;                           // tc in {0..20}
        int cidx = cls < 0 ? 0 : cls;
        float pcls = spf[qcell * 30 + 10 + cidx];        // dynamic LDS read (staged above)
        float lcls = csum_tot - 2.0f * pcls + 1.0f;

        float obj_loss   = dcf * dcf + 5.0f * (d0 * d0 + d1 * d1) + lcls;
        float noobj_loss = 0.5f * (s[4] * s[4] + s[9] * s[9]);
        val = (tc != 0.0f) ? obj_loss : noobj_loss;
    }

    // ---- wave reduce -> one partial per tile; no barrier ----
#pragma unroll
    for (int off = 32; off > 0; off >>= 1) {
        val += __shfl_down(val, off, 64);
    }
    if (lane == 0) partials[tile] = val;
}

__global__ __launch_bounds__(256) void reduce_kernel(const float* __restrict__ partials,
                                                     float* __restrict__ out) {
    int tid = threadIdx.x;
    float ssum = 0.0f;
#pragma unroll
    for (int k = 0; k < 98; ++k) {           // 98 * 256 = 25088 exact
        ssum += partials[k * 256 + tid];
    }
#pragma unroll
    for (int off = 32; off > 0; off >>= 1) {
        ssum += __shfl_down(ssum, off, 64);
    }
    __shared__ float wsum[4];
    int lane = tid & 63;
    int wid  = tid >> 6;
    if (lane == 0) wsum[wid] = ssum;
    __syncthreads();
    if (tid == 0) {
        out[0] = (wsum[0] + wsum[1] + wsum[2] + wsum[3]) * (1.0f / 1024.0f);
    }
}

extern "C" void kernel_launch(void* const* d_in, const int* in_sizes, int n_in,
                              void* d_out, int out_size, void* d_ws, size_t ws_size,
                              hipStream_t stream) {
    const float2* y_pred2 = (const float2*)d_in[0];
    const float*  y_true  = (const float*)d_in[1];
    float* out = (float*)d_out;
    float* partials = (float*)d_ws;   // 25088 floats, fully overwritten each call

    yolo_loss_kernel<<<NBLOCKS, BLOCK, 0, stream>>>(y_pred2, y_true, partials);
    reduce_kernel<<<1, 256, 0, stream>>>(partials, out);
}